// Round 1
// baseline (196.835 us; speedup 1.0000x reference)
//
#include <hip/hip_runtime.h>

#define D_FEAT 128
#define THRESH 0.01f
#define EPS_F  1e-8f

// Exact-scalar fallback for a single edge (replicates numpy's 8-accumulator
// pairwise sum bit-exactly). Only executed if the mirror-structure check
// fails (never, for this benchmark's inputs) — correctness path, not perf.
__device__ float edge_out_scalar(const float* __restrict__ feat,
                                 float w, int s, int d) {
#pragma clang fp contract(off)
    const float* fs = feat + (size_t)s * D_FEAT;
    const float* fd = feat + (size_t)d * D_FEAT;
    float r[8], rs[8], rd[8];
#pragma unroll
    for (int j = 0; j < 8; ++j) {
        float a = fs[j], b = fd[j];
        r[j]  = a * b;
        rs[j] = a * a;
        rd[j] = b * b;
    }
    for (int k = 1; k < 16; ++k) {
#pragma unroll
        for (int j = 0; j < 8; ++j) {
            float a = fs[8 * k + j], b = fd[8 * k + j];
            r[j]  = r[j]  + a * b;
            rs[j] = rs[j] + a * a;
            rd[j] = rd[j] + b * b;
        }
    }
    float inner = ((r[0]  + r[1])  + (r[2]  + r[3]))  + ((r[4]  + r[5])  + (r[6]  + r[7]));
    float ss    = ((rs[0] + rs[1]) + (rs[2] + rs[3])) + ((rs[4] + rs[5]) + (rs[6] + rs[7]));
    float dd    = ((rd[0] + rd[1]) + (rd[2] + rd[3])) + ((rd[4] + rd[5]) + (rd[6] + rd[7]));
    float ns = __fsqrt_rn(ss);
    float nd = __fsqrt_rn(dd);
    float denom = ns * nd + EPS_F;   // mul then add, contraction off (matches numpy)
    float sim = inner / denom;       // IEEE fp32 divide
    float keep = (sim >= THRESH) ? 1.0f : 0.0f;
    float diag = (s == d) ? 2.0f : 1.0f;
    return (w * keep) * diag;
}

// 2 lanes per undirected pair. Lane `half` covers numpy accumulator classes
// [4*half, 4*half+4): element index i = 8k + 4*half + m, so each float4 load
// at float4-index (2k + half) contributes term k (in order) to classes
// 4*half+m. Sequential k-loop == numpy's sequential accumulator update.
// Final combine ((r0+r1)+(r2+r3)) + ((r4+r5)+(r6+r7)) done in-lane + one
// __shfl_xor add (IEEE addition is commutative -> bit-identical on both lanes).
__global__ __launch_bounds__(256) void jaccard_edge_kernel(
    const int* __restrict__ ei, const float* __restrict__ w,
    const float* __restrict__ feat, float* __restrict__ out,
    int P, int E)
{
#pragma clang fp contract(off)
    int t    = blockIdx.x * blockDim.x + threadIdx.x;
    int pair = t >> 1;
    int half = t & 1;
    if (pair >= P) return;

    int src = ei[pair];
    int dst = ei[E + pair];

    const float4* fs = (const float4*)(feat + (size_t)src * D_FEAT);
    const float4* fd = (const float4*)(feat + (size_t)dst * D_FEAT);

    float r[4], rs[4], rd[4];
    {
        float4 a = fs[half];
        float4 b = fd[half];
        r[0]  = a.x * b.x; r[1]  = a.y * b.y; r[2]  = a.z * b.z; r[3]  = a.w * b.w;
        rs[0] = a.x * a.x; rs[1] = a.y * a.y; rs[2] = a.z * a.z; rs[3] = a.w * a.w;
        rd[0] = b.x * b.x; rd[1] = b.y * b.y; rd[2] = b.z * b.z; rd[3] = b.w * b.w;
    }
#pragma unroll
    for (int k = 1; k < 16; ++k) {
        float4 a = fs[2 * k + half];
        float4 b = fd[2 * k + half];
        r[0]  = r[0]  + a.x * b.x;
        r[1]  = r[1]  + a.y * b.y;
        r[2]  = r[2]  + a.z * b.z;
        r[3]  = r[3]  + a.w * b.w;
        rs[0] = rs[0] + a.x * a.x;
        rs[1] = rs[1] + a.y * a.y;
        rs[2] = rs[2] + a.z * a.z;
        rs[3] = rs[3] + a.w * a.w;
        rd[0] = rd[0] + b.x * b.x;
        rd[1] = rd[1] + b.y * b.y;
        rd[2] = rd[2] + b.z * b.z;
        rd[3] = rd[3] + b.w * b.w;
    }
    float A  = (r[0]  + r[1])  + (r[2]  + r[3]);
    float As = (rs[0] + rs[1]) + (rs[2] + rs[3]);
    float Ad = (rd[0] + rd[1]) + (rd[2] + rd[3]);

    float inner = A  + __shfl_xor(A, 1, 64);
    float ss    = As + __shfl_xor(As, 1, 64);
    float dd    = Ad + __shfl_xor(Ad, 1, 64);

    float ns    = __fsqrt_rn(ss);
    float nd    = __fsqrt_rn(dd);
    float denom = ns * nd + EPS_F;   // separate mul + add (numpy order)
    float sim   = inner / denom;     // IEEE fp32 divide
    float keep  = (sim >= THRESH) ? 1.0f : 0.0f;

    if (half == 0) {
        float diag = (src == dst) ? 2.0f : 1.0f;
        out[pair] = (w[pair] * keep) * diag;

        int m = P + pair;
        if (m < E) {
            int s2 = ei[m];
            int d2 = ei[E + m];
            if (s2 == dst && d2 == src) {
                // Mirror edge: products commute, same summation order ->
                // bit-identical sim/keep. diag identical (s2==d2 iff src==dst).
                out[m] = (w[m] * keep) * diag;
            } else {
                out[m] = edge_out_scalar(feat, w[m], s2, d2);
            }
        }
    }
}

extern "C" void kernel_launch(void* const* d_in, const int* in_sizes, int n_in,
                              void* d_out, int out_size, void* d_ws, size_t ws_size,
                              hipStream_t stream) {
    const int*   ei   = (const int*)d_in[0];     // [2, E] flattened (int32)
    const float* w    = (const float*)d_in[1];   // [E]
    const float* feat = (const float*)d_in[2];   // [N, 128]
    float*       out  = (float*)d_out;           // [E]

    int E = in_sizes[1];
    int P = E - E / 2;          // ceil(E/2); == E/2 for even E
    int threads = 2 * P;
    int block = 256;
    int grid = (threads + block - 1) / block;
    jaccard_edge_kernel<<<grid, block, 0, stream>>>(ei, w, feat, out, P, E);
}

// Round 2
// 155.924 us; speedup vs baseline: 1.2624x; 1.2624x over previous
//
#include <hip/hip_runtime.h>
#include <hip/hip_fp16.h>

#define D_FEAT 128
#define THRESH 0.01f
#define EPS_F  1e-8f

// ---------------------------------------------------------------------------
// Exact helpers: bit-exact replication of numpy's fp32 pipeline
// (8-accumulator pairwise sum). Proven absmax=0 in round 1.
// ---------------------------------------------------------------------------

// Fully-scalar exact path for one arbitrary edge (mirror-structure fallback).
__device__ float edge_out_scalar(const float* __restrict__ feat,
                                 float w, int s, int d) {
#pragma clang fp contract(off)
    const float* fs = feat + (size_t)s * D_FEAT;
    const float* fd = feat + (size_t)d * D_FEAT;
    float r[8], rs[8], rd[8];
#pragma unroll
    for (int j = 0; j < 8; ++j) {
        float a = fs[j], b = fd[j];
        r[j]  = a * b;
        rs[j] = a * a;
        rd[j] = b * b;
    }
    for (int k = 1; k < 16; ++k) {
#pragma unroll
        for (int j = 0; j < 8; ++j) {
            float a = fs[8 * k + j], b = fd[8 * k + j];
            r[j]  = r[j]  + a * b;
            rs[j] = rs[j] + a * a;
            rd[j] = rd[j] + b * b;
        }
    }
    float inner = ((r[0]  + r[1])  + (r[2]  + r[3]))  + ((r[4]  + r[5])  + (r[6]  + r[7]));
    float ss    = ((rs[0] + rs[1]) + (rs[2] + rs[3])) + ((rs[4] + rs[5]) + (rs[6] + rs[7]));
    float dd    = ((rd[0] + rd[1]) + (rd[2] + rd[3])) + ((rd[4] + rd[5]) + (rd[6] + rd[7]));
    float ns = __fsqrt_rn(ss);
    float nd = __fsqrt_rn(dd);
    float denom = ns * nd + EPS_F;
    float sim = inner / denom;
    float keep = (sim >= THRESH) ? 1.0f : 0.0f;
    float diag = (s == d) ? 2.0f : 1.0f;
    return (w * keep) * diag;
}

// Two-lane exact sim: lanes h=0,1 (partners under shfl_xor 1) split the 8
// numpy accumulator classes 4+4; k-loop is sequential (numpy order); the
// final cross-lane add is IEEE-commutative -> bit-identical on both lanes.
__device__ __forceinline__ float exact_sim_pairlanes(const float* __restrict__ feat,
                                                     int src, int dst, int h) {
#pragma clang fp contract(off)
    const float4* fs = (const float4*)(feat + (size_t)src * D_FEAT);
    const float4* fd = (const float4*)(feat + (size_t)dst * D_FEAT);
    float r[4], rs[4], rd[4];
    {
        float4 a = fs[h];
        float4 b = fd[h];
        r[0]  = a.x * b.x; r[1]  = a.y * b.y; r[2]  = a.z * b.z; r[3]  = a.w * b.w;
        rs[0] = a.x * a.x; rs[1] = a.y * a.y; rs[2] = a.z * a.z; rs[3] = a.w * a.w;
        rd[0] = b.x * b.x; rd[1] = b.y * b.y; rd[2] = b.z * b.z; rd[3] = b.w * b.w;
    }
#pragma unroll
    for (int k = 1; k < 16; ++k) {
        float4 a = fs[2 * k + h];
        float4 b = fd[2 * k + h];
        r[0]  = r[0]  + a.x * b.x;
        r[1]  = r[1]  + a.y * b.y;
        r[2]  = r[2]  + a.z * b.z;
        r[3]  = r[3]  + a.w * b.w;
        rs[0] = rs[0] + a.x * a.x;
        rs[1] = rs[1] + a.y * a.y;
        rs[2] = rs[2] + a.z * a.z;
        rs[3] = rs[3] + a.w * a.w;
        rd[0] = rd[0] + b.x * b.x;
        rd[1] = rd[1] + b.y * b.y;
        rd[2] = rd[2] + b.z * b.z;
        rd[3] = rd[3] + b.w * b.w;
    }
    float A  = (r[0]  + r[1])  + (r[2]  + r[3]);
    float As = (rs[0] + rs[1]) + (rs[2] + rs[3]);
    float Ad = (rd[0] + rd[1]) + (rd[2] + rd[3]);

    float inner = A  + __shfl_xor(A, 1, 64);
    float ssE   = As + __shfl_xor(As, 1, 64);
    float ddE   = Ad + __shfl_xor(Ad, 1, 64);

    float ns    = __fsqrt_rn(ssE);
    float nd    = __fsqrt_rn(ddE);
    float den   = ns * nd + EPS_F;
    return inner / den;
}

// ---------------------------------------------------------------------------
// Round-1 proven kernel: kept verbatim as fallback (ws too small, odd sizes).
// ---------------------------------------------------------------------------
__global__ __launch_bounds__(256) void jaccard_edge_kernel(
    const int* __restrict__ ei, const float* __restrict__ w,
    const float* __restrict__ feat, float* __restrict__ out,
    int P, int E)
{
    int t    = blockIdx.x * blockDim.x + threadIdx.x;
    int pair = t >> 1;
    int half = t & 1;
    if (pair >= P) return;

    int src = ei[pair];
    int dst = ei[E + pair];

    float sim  = exact_sim_pairlanes(feat, src, dst, half);
    float keep = (sim >= THRESH) ? 1.0f : 0.0f;

    if (half == 0) {
        float diag = (src == dst) ? 2.0f : 1.0f;
        out[pair] = (w[pair] * keep) * diag;
        int m = P + pair;
        if (m < E) {
            int s2 = ei[m];
            int d2 = ei[E + m];
            if (s2 == dst && d2 == src) out[m] = (w[m] * keep) * diag;
            else                        out[m] = edge_out_scalar(feat, w[m], s2, d2);
        }
    }
}

// ---------------------------------------------------------------------------
// Pass A: fp32 -> fp16 (RNE) conversion, fully coalesced, 8 elems/thread.
// ---------------------------------------------------------------------------
__global__ __launch_bounds__(256) void convert_f16_kernel(
    const float* __restrict__ feat, __half* __restrict__ hfeat, int n8)
{
    int t = blockIdx.x * blockDim.x + threadIdx.x;
    if (t >= n8) return;
    const float4* p = (const float4*)feat + 2 * (size_t)t;
    float4 a = p[0];
    float4 b = p[1];
    __half2 h0 = __floats2half2_rn(a.x, a.y);
    __half2 h1 = __floats2half2_rn(a.z, a.w);
    __half2 h2 = __floats2half2_rn(b.x, b.y);
    __half2 h3 = __floats2half2_rn(b.z, b.w);
    uint4 o;
    o.x = *reinterpret_cast<unsigned int*>(&h0);
    o.y = *reinterpret_cast<unsigned int*>(&h1);
    o.z = *reinterpret_cast<unsigned int*>(&h2);
    o.w = *reinterpret_cast<unsigned int*>(&h3);
    reinterpret_cast<uint4*>(hfeat)[(size_t)t] = o;
}

// accumulate 2 elements (one packed uint) into dot / sum|ab| / ss / dd
__device__ __forceinline__ void acc2(unsigned int ua, unsigned int ub,
                                     float& dot, float& sab, float& ss, float& dd) {
    float2 fa = __half22float2(*reinterpret_cast<const __half2*>(&ua));
    float2 fb = __half22float2(*reinterpret_cast<const __half2*>(&ub));
    float p0 = fa.x * fb.x, p1 = fa.y * fb.y;
    dot += p0 + p1;
    sab += fabsf(p0) + fabsf(p1);
    ss  += fa.x * fa.x + fa.y * fa.y;
    dd  += fb.x * fb.x + fb.y * fb.y;
}

// ---------------------------------------------------------------------------
// Pass B: fp16 gather-dot with rigorous interval bound; exact fp32 fallback
// for borderline pairs (~1%). 4 lanes per pair; lane q reads bytes
// [64k + 16q) of each 256B row -> quad covers one 64B line per row per iter.
// ---------------------------------------------------------------------------
__global__ __launch_bounds__(256) void jaccard_edge_f16_kernel(
    const int* __restrict__ ei, const float* __restrict__ w,
    const float* __restrict__ feat, const __half* __restrict__ hfeat,
    float* __restrict__ out, int P, int E)
{
    int t    = blockIdx.x * blockDim.x + threadIdx.x;
    int pair = t >> 2;
    int q    = t & 3;
    if (pair >= P) return;

    int src = ei[pair];
    int dst = ei[E + pair];

    const uint4* ha = (const uint4*)(hfeat + (size_t)src * D_FEAT);
    const uint4* hb = (const uint4*)(hfeat + (size_t)dst * D_FEAT);

    float dot = 0.f, sab = 0.f, ss = 0.f, dd = 0.f;
#pragma unroll
    for (int k = 0; k < 4; ++k) {
        uint4 ua = ha[4 * k + q];
        uint4 ub = hb[4 * k + q];
        acc2(ua.x, ub.x, dot, sab, ss, dd);
        acc2(ua.y, ub.y, dot, sab, ss, dd);
        acc2(ua.z, ub.z, dot, sab, ss, dd);
        acc2(ua.w, ub.w, dot, sab, ss, dd);
    }
    // quad butterfly: identical bit patterns on all 4 lanes (IEEE a+b==b+a)
    dot += __shfl_xor(dot, 1, 64); dot += __shfl_xor(dot, 2, 64);
    sab += __shfl_xor(sab, 1, 64); sab += __shfl_xor(sab, 2, 64);
    ss  += __shfl_xor(ss,  1, 64); ss  += __shfl_xor(ss,  2, 64);
    dd  += __shfl_xor(dd,  1, 64); dd  += __shfl_xor(dd,  2, 64);

    float na  = __fsqrt_rn(ss);
    float nb  = __fsqrt_rn(dd);
    float den = na * nb + EPS_F;
    float sim = dot / den;

    // Rigorous |sim_numpy - sim| bound:
    //  - fp16 RNE input rounding: (2*2^-11 + 2^-22) * sum|ab|  -> 9.8e-4*S
    //  - fp32 product/sum rounding both sides (any order): ~130*2^-24*S
    //  - denominator relative error ~1e-3 -> * |sim|
    //  Constants inflated to 1.2e-3 (20% headroom, covers fp32 eval of bound).
    //  Subnormal-rounding slack: 2^-25*sqrt(128)*(1/na+1/nb) term; na==0 -> inf
    //  -> borderline -> exact path (self-guarding).
    float bnd = 1.2e-3f * (sab / den) + 1.2e-3f * fabsf(sim)
              + 3.5e-7f * (1.0f / na + 1.0f / nb) + 1e-7f;
    float diff = sim - THRESH;

    float keep;
    if (fabsf(diff) > bnd) {          // quad-uniform: all 4 lanes bit-identical
        keep = (diff >= 0.f) ? 1.0f : 0.0f;
    } else {
        float se = 0.f;
        if (q < 2) se = exact_sim_pairlanes(feat, src, dst, q);  // lanes 0,1 active together
        keep = (se >= THRESH) ? 1.0f : 0.0f;   // valid on lane q==0 (the writer)
    }

    if (q == 0) {
        float diag = (src == dst) ? 2.0f : 1.0f;
        out[pair] = (w[pair] * keep) * diag;
        int m = P + pair;
        if (m < E) {
            int s2 = ei[m];
            int d2 = ei[E + m];
            if (s2 == dst && d2 == src) out[m] = (w[m] * keep) * diag;
            else                        out[m] = edge_out_scalar(feat, w[m], s2, d2);
        }
    }
}

extern "C" void kernel_launch(void* const* d_in, const int* in_sizes, int n_in,
                              void* d_out, int out_size, void* d_ws, size_t ws_size,
                              hipStream_t stream) {
    const int*   ei   = (const int*)d_in[0];     // [2, E] flattened (int32)
    const float* w    = (const float*)d_in[1];   // [E]
    const float* feat = (const float*)d_in[2];   // [N, 128]
    float*       out  = (float*)d_out;           // [E]

    int E = in_sizes[1];
    int P = E - E / 2;                 // ceil(E/2)
    long nfeat = in_sizes[2];
    size_t need = (size_t)nfeat * sizeof(__half);

    if (ws_size < need || (nfeat & 7) != 0) {
        // Fallback: round-1 proven exact kernel.
        int threads = 2 * P;
        int grid = (threads + 255) / 256;
        jaccard_edge_kernel<<<grid, 256, 0, stream>>>(ei, w, feat, out, P, E);
        return;
    }

    __half* hfeat = (__half*)d_ws;
    int n8 = (int)(nfeat / 8);
    convert_f16_kernel<<<(n8 + 255) / 256, 256, 0, stream>>>(feat, hfeat, n8);

    int threads = 4 * P;
    int grid = (threads + 255) / 256;
    jaccard_edge_f16_kernel<<<grid, 256, 0, stream>>>(ei, w, feat, hfeat, out, P, E);
}